// Round 12
// baseline (301.394 us; speedup 1.0000x reference)
//
#include <hip/hip_runtime.h>
#include <hip/hip_fp16.h>

// RoIAlign3D: features (B=2, C=256, 64,64,64) f32, proposals (B=2, N=512, 6) f32
// out: (B*N, C, 7, 7, 7) f32
//
// kernel1: bucket 3584 (roi,iz) entries per batch by z0=floor(gz) into CSR +
//   32 B record {x1p,sx,y1p,sy, wz,out_off,-,-}.
// kernel2: block = (z0, slice). 512 thr, LDS 33.8 KB -> 4 blocks/CU: four
//   independent stage/compute phases per CU keep global loads in flight
//   continuously (R8-R11 all bottlenecked on stage-burst duty cycle at
//   2 blocks/CU). Stage planes z0,z0+1 (32 KB f32) of one channel slice,
//   convert to z-pair f16 slots: slot64(y,x) = {pk(h[x],h[x+1])@z0,
//   pk(...)@z0+1}. Per point: ONE ds_read2_b64 -> all 8 corners.
//   Slice-fastest order pins slice s to XCD s%8 -> plane re-read (z0 round
//   -> z0+1 round) is XCD-L2-local.
// Coords in [0,63): floor<=62, +1<=63 -> no clamping; slot x=63's upper half
//   is garbage but never read (x0<=62).

#define B_      2
#define C_      256
#define N_      512
#define NENT    (N_ * 7)
#define SP      66                  // slots per row (64 used + 2 pad)
#define THREADS 512
#define GROUPS  10                  // 10*49 = 490 active lanes
#define REC_F_BASE 128
#define WS_NEEDED ((size_t)REC_F_BASE * 4 + (size_t)B_ * NENT * 8 * 4)

typedef _Float16 h2v __attribute__((ext_vector_type(2)));

__device__ __forceinline__ float gcoord(float lo, float hi, int i) {
    return lo + (hi - lo) * (1.0f / 6.0f) * (float)i;
}

__device__ __forceinline__ uint32_t pkrtz(float a, float b) {
    auto h = __builtin_amdgcn_cvt_pkrtz(a, b);
    return __builtin_bit_cast(uint32_t, h);
}

// (1-wx)*v.lo + wx*v.hi with f32 accumulation
__device__ __forceinline__ float xlerp(uint32_t pkv, uint32_t pkw) {
#if __has_builtin(__builtin_amdgcn_fdot2)
    return __builtin_amdgcn_fdot2(__builtin_bit_cast(h2v, pkv),
                                  __builtin_bit_cast(h2v, pkw), 0.0f, false);
#else
    h2v v = __builtin_bit_cast(h2v, pkv);
    h2v w = __builtin_bit_cast(h2v, pkw);
    return (float)v[0] * (float)w[0] + (float)v[1] * (float)w[1];
#endif
}

// ---- kernel 1: bucket + per-entry record ----
__global__ __launch_bounds__(256) void bucket_kernel(
    const float* __restrict__ props, int* __restrict__ wsi, float* __restrict__ wsf)
{
    int b = blockIdx.x;
    __shared__ int counts[63];
    __shared__ int starts[64];
    __shared__ int cursors[63];
    int tid = threadIdx.x;
    if (tid < 63) counts[tid] = 0;
    __syncthreads();
    for (int e = tid; e < NENT; e += 256) {
        int n = e / 7, iz = e - n * 7;
        const float* pr = props + (size_t)(b * N_ + n) * 6;
        float gz = gcoord(pr[2], pr[5], iz);
        int z0 = min(max((int)gz, 0), 62);
        atomicAdd(&counts[z0], 1);
    }
    __syncthreads();
    if (tid == 0) {
        int s = 0;
        for (int k = 0; k < 63; ++k) { starts[k] = s; s += counts[k]; }
        starts[63] = s;
    }
    __syncthreads();
    if (tid < 63) cursors[tid] = starts[tid];
    __syncthreads();
    for (int e = tid; e < NENT; e += 256) {
        int n = e / 7, iz = e - n * 7;
        const float* pr = props + (size_t)(b * N_ + n) * 6;
        float x1p = pr[0], y1p = pr[1], z1p = pr[2];
        float x2p = pr[3], y2p = pr[4], z2p = pr[5];
        float gz = gcoord(z1p, z2p, iz);
        int z0 = min(max((int)gz, 0), 62);
        float wz = gz - (float)z0;
        int pos = atomicAdd(&cursors[z0], 1);
        int off = (b * N_ + n) * (C_ * 343) + iz * 49;
        float* r = wsf + REC_F_BASE + (size_t)(b * NENT + pos) * 8;
        r[0] = x1p; r[1] = (x2p - x1p) * (1.0f / 6.0f);
        r[2] = y1p; r[3] = (y2p - y1p) * (1.0f / 6.0f);
        r[4] = wz;  r[5] = __int_as_float(off);
        r[6] = 0.0f; r[7] = 0.0f;
    }
    if (tid < 64) wsi[b * 64 + tid] = starts[tid];
}

// ---- kernel 2: block = (z0, slice); 512 thr; 4 blocks/CU ----
__global__ __launch_bounds__(THREADS, 8) void roialign3d_small_kernel(
    const float* __restrict__ feat,
    const int* __restrict__ wsi,
    const float* __restrict__ wsf,
    float* __restrict__ out)
{
    __shared__ __align__(16) uint2 pk2[64 * SP];   // 33792 B -> 4 blocks/CU

    int bid = blockIdx.x;
    int s   = bid & 511;           // slice fastest -> slice s on XCD s%8 always
    int z0  = bid >> 9;            // 0..62
    int b   = s >> 8;
    int c   = s & 255;
    int tid = threadIdx.x;

    int base = wsi[b * 64 + z0];
    int end  = wsi[b * 64 + z0 + 1];
    if (base == end) return;       // empty bucket: skip staging entirely

    const float* vol = feat + ((size_t)s << 18) + ((size_t)z0 << 12);

    // ---- stage: 2 planes (32 KB) of one slice; 4 float4 loads/thread ----
    int y  = tid >> 3;
    int x8 = (tid & 7) << 3;
    const float* src = vol + y * 64 + x8;
    float4 p0a = *(const float4*)(src);
    float4 p0b = *(const float4*)(src + 4);
    float4 p1a = *(const float4*)(src + 4096);
    float4 p1b = *(const float4*)(src + 4100);

    // dense lane map + record prefetch (behind plane loads)
    int g = tid / 49;
    int p = tid - g * 49;
    int iy = p / 7;
    float fx = (float)(p - iy * 7);
    float fy = (float)iy;
    const float4* recs = (const float4*)(wsf + REC_F_BASE);
    const int rbase = b * NENT;
    int myEnd = (g < GROUPS) ? end : base;
    int e = base + g;
    float4 rA, rB, rAn, rBn;
    if (e < myEnd) {
        rA = recs[(size_t)(rbase + e) * 2];
        rB = recs[(size_t)(rbase + e) * 2 + 1];
        if (e + GROUPS < myEnd) {
            rAn = recs[(size_t)(rbase + e + GROUPS) * 2];
            rBn = recs[(size_t)(rbase + e + GROUPS) * 2 + 1];
        }
    }

    // ---- convert + write: slot64(y,x) = {xpair@z0, xpair@z0+1} ----
    {
        float n0 = __shfl_down(p0a.x, 1);   // next thread's first f32, plane z0
        float n1 = __shfl_down(p1a.x, 1);   // (garbage at row/wave edge: slot
                                            //  x=63 upper half, never read)
        uint4* d = (uint4*)&pk2[y * SP + x8];
        uint4 w0, w1, w2, w3;
        w0.x = pkrtz(p0a.x, p0a.y); w0.y = pkrtz(p1a.x, p1a.y);
        w0.z = pkrtz(p0a.y, p0a.z); w0.w = pkrtz(p1a.y, p1a.z);
        w1.x = pkrtz(p0a.z, p0a.w); w1.y = pkrtz(p1a.z, p1a.w);
        w1.z = pkrtz(p0a.w, p0b.x); w1.w = pkrtz(p1a.w, p1b.x);
        w2.x = pkrtz(p0b.x, p0b.y); w2.y = pkrtz(p1b.x, p1b.y);
        w2.z = pkrtz(p0b.y, p0b.z); w2.w = pkrtz(p1b.y, p1b.z);
        w3.x = pkrtz(p0b.z, p0b.w); w3.y = pkrtz(p1b.z, p1b.w);
        w3.z = pkrtz(p0b.w, n0);    w3.w = pkrtz(p1b.w, n1);
        d[0] = w0; d[1] = w1; d[2] = w2; d[3] = w3;
    }
    __syncthreads();

    // ---- entry loop: one ds_read2_b64 per point ----
    float* outc = out + (size_t)c * 343;
    while (e < myEnd) {
        float gx = fmaf(rA.y, fx, rA.x);
        float gy = fmaf(rA.w, fy, rA.z);
        int x0 = (int)gx, y0 = (int)gy;
        float wx = __builtin_amdgcn_fractf(gx);
        float wy = __builtin_amdgcn_fractf(gy);
        uint32_t pw = pkrtz(1.0f - wx, wx);
        float wz = rB.x;
        int offc = __float_as_int(rB.y);
        int sl = y0 * SP + x0;
        uint2 q0 = pk2[sl];        // rows y0   : {z0, z0+1}
        uint2 q1 = pk2[sl + SP];   // rows y0+1 : {z0, z0+1}

        // rotate record pipeline; prefetch e+2*GROUPS
        float4 tA = rAn, tB = rBn;
        int e2 = e + 2 * GROUPS;
        if (e2 < myEnd) {
            rAn = recs[(size_t)(rbase + e2) * 2];
            rBn = recs[(size_t)(rbase + e2) * 2 + 1];
        }

        float c00 = xlerp(q0.x, pw);   // z0  , y0
        float c10 = xlerp(q0.y, pw);   // z0+1, y0
        float c01 = xlerp(q1.x, pw);   // z0  , y0+1
        float c11 = xlerp(q1.y, pw);   // z0+1, y0+1
        float d0 = fmaf(c01 - c00, wy, c00);
        float d1 = fmaf(c11 - c10, wy, c10);
        outc[offc + p] = fmaf(d1 - d0, wz, d0);

        e += GROUPS; rA = tA; rB = tB;
    }
}

// ---- fallback (ws too small): round-1 kernel, known correct ----
__global__ __launch_bounds__(128) void roialign3d_fallback(
    const float* __restrict__ feat, const float* __restrict__ props,
    float* __restrict__ out)
{
    int bid = blockIdx.x;
    int xcd = bid & 7;
    int j   = bid >> 3;
    int s   = xcd + ((j >> 9) << 3);
    int n   = j & 511;
    int b   = s >> 8;
    int c   = s & 255;
    const float* prop = props + ((size_t)(b * N_ + n)) * 6;
    float x1p = prop[0], y1p = prop[1], z1p = prop[2];
    float x2p = prop[3], y2p = prop[4], z2p = prop[5];
    float sx = (x2p - x1p) * (1.0f / 6.0f);
    float sy = (y2p - y1p) * (1.0f / 6.0f);
    float sz = (z2p - z1p) * (1.0f / 6.0f);
    const float* vol = feat + (size_t)s * (64 * 64 * 64);
    float* o = out + ((size_t)(b * N_ + n) * C_ + c) * 343;
    for (int p = threadIdx.x; p < 343; p += 128) {
        int iz = p / 49, r = p - iz * 49, iy = r / 7, ix = r - iy * 7;
        float gx = x1p + sx * ix, gy = y1p + sy * iy, gz = z1p + sz * iz;
        int x0 = (int)gx, y0 = (int)gy, z0 = (int)gz;
        float wx = gx - x0, wy = gy - y0, wz = gz - z0;
        int x1 = min(x0 + 1, 63), y1 = min(y0 + 1, 63), z1 = min(z0 + 1, 63);
        const float* p00 = vol + ((z0 * 64 + y0) << 6);
        const float* p01 = vol + ((z0 * 64 + y1) << 6);
        const float* p10 = vol + ((z1 * 64 + y0) << 6);
        const float* p11 = vol + ((z1 * 64 + y1) << 6);
        float c00 = p00[x0] + (p00[x1] - p00[x0]) * wx;
        float c01 = p01[x0] + (p01[x1] - p01[x0]) * wx;
        float c10 = p10[x0] + (p10[x1] - p10[x0]) * wx;
        float c11 = p11[x0] + (p11[x1] - p11[x0]) * wx;
        float d0 = c00 + (c01 - c00) * wy;
        float d1 = c10 + (c11 - c10) * wy;
        o[p] = d0 + (d1 - d0) * wz;
    }
}

extern "C" void kernel_launch(void* const* d_in, const int* in_sizes, int n_in,
                              void* d_out, int out_size, void* d_ws, size_t ws_size,
                              hipStream_t stream) {
    const float* feat  = (const float*)d_in[0];
    const float* props = (const float*)d_in[1];
    float* out = (float*)d_out;

    if (ws_size < WS_NEEDED) {
        roialign3d_fallback<<<B_ * C_ * N_, 128, 0, stream>>>(feat, props, out);
        return;
    }
    int*   wsi = (int*)d_ws;
    float* wsf = (float*)d_ws;
    bucket_kernel<<<B_, 256, 0, stream>>>(props, wsi, wsf);
    roialign3d_small_kernel<<<63 * 512, THREADS, 0, stream>>>(feat, wsi, wsf, out);
}

// Round 13
// 293.316 us; speedup vs baseline: 1.0275x; 1.0275x over previous
//
#include <hip/hip_runtime.h>
#include <hip/hip_fp16.h>

// RoIAlign3D: features (B=2, C=256, 64,64,64) f32, proposals (B=2, N=512, 6) f32
// out: (B*N, C, 7, 7, 7) f32
//
// kernel1: bucket 3584 (roi,iz) entries per batch by z0=floor(gz) into CSR +
//   32 B record {x1p,sx,y1p,sy, wz,out_off,-,-}.
// kernel2: block = (z0, slice), 512 thr, 33.8 KB LDS -> 4 blocks/CU.
//   Stage planes z0,z0+1 as z-pair f16 slots: slot64(y,x) =
//   {pk(h[x],h[x+1])@z0, pk(...)@z0+1}; one ds_read2_b64 -> all 8 corners.
//   LANE = (entry, iy): each lane computes the full 7-point x-row of one
//   entry -> gy/y0/wy/record/store-base amortized over 7 points (the
//   sum-of-issue-slots across VALU+LDS+VMEM is the measured invariant
//   ~300us in R8-R12; this cuts it ~2x on the non-LDS side).
//   9 entries/wave (lane 63 idle), 72 entries per block-pass.
// Coords in [0,63): floor<=62, +1<=63 -> no clamping; slot x=63's upper
//   half is garbage but never read (x0<=62).

#define B_      2
#define C_      256
#define N_      512
#define NENT    (N_ * 7)
#define SP      66                  // slots per row (64 used + 2 pad)
#define THREADS 512
#define EPP     72                  // entries per block-pass: 8 waves * 9
#define REC_F_BASE 128
#define WS_NEEDED ((size_t)REC_F_BASE * 4 + (size_t)B_ * NENT * 8 * 4)

typedef _Float16 h2v __attribute__((ext_vector_type(2)));

__device__ __forceinline__ float gcoord(float lo, float hi, int i) {
    return lo + (hi - lo) * (1.0f / 6.0f) * (float)i;
}

__device__ __forceinline__ uint32_t pkrtz(float a, float b) {
    auto h = __builtin_amdgcn_cvt_pkrtz(a, b);
    return __builtin_bit_cast(uint32_t, h);
}

// (1-wx)*v.lo + wx*v.hi with f32 accumulation
__device__ __forceinline__ float xlerp(uint32_t pkv, uint32_t pkw) {
#if __has_builtin(__builtin_amdgcn_fdot2)
    return __builtin_amdgcn_fdot2(__builtin_bit_cast(h2v, pkv),
                                  __builtin_bit_cast(h2v, pkw), 0.0f, false);
#else
    h2v v = __builtin_bit_cast(h2v, pkv);
    h2v w = __builtin_bit_cast(h2v, pkw);
    return (float)v[0] * (float)w[0] + (float)v[1] * (float)w[1];
#endif
}

// ---- kernel 1: bucket + per-entry record ----
__global__ __launch_bounds__(256) void bucket_kernel(
    const float* __restrict__ props, int* __restrict__ wsi, float* __restrict__ wsf)
{
    int b = blockIdx.x;
    __shared__ int counts[63];
    __shared__ int starts[64];
    __shared__ int cursors[63];
    int tid = threadIdx.x;
    if (tid < 63) counts[tid] = 0;
    __syncthreads();
    for (int e = tid; e < NENT; e += 256) {
        int n = e / 7, iz = e - n * 7;
        const float* pr = props + (size_t)(b * N_ + n) * 6;
        float gz = gcoord(pr[2], pr[5], iz);
        int z0 = min(max((int)gz, 0), 62);
        atomicAdd(&counts[z0], 1);
    }
    __syncthreads();
    if (tid == 0) {
        int s = 0;
        for (int k = 0; k < 63; ++k) { starts[k] = s; s += counts[k]; }
        starts[63] = s;
    }
    __syncthreads();
    if (tid < 63) cursors[tid] = starts[tid];
    __syncthreads();
    for (int e = tid; e < NENT; e += 256) {
        int n = e / 7, iz = e - n * 7;
        const float* pr = props + (size_t)(b * N_ + n) * 6;
        float x1p = pr[0], y1p = pr[1], z1p = pr[2];
        float x2p = pr[3], y2p = pr[4], z2p = pr[5];
        float gz = gcoord(z1p, z2p, iz);
        int z0 = min(max((int)gz, 0), 62);
        float wz = gz - (float)z0;
        int pos = atomicAdd(&cursors[z0], 1);
        int off = (b * N_ + n) * (C_ * 343) + iz * 49;
        float* r = wsf + REC_F_BASE + (size_t)(b * NENT + pos) * 8;
        r[0] = x1p; r[1] = (x2p - x1p) * (1.0f / 6.0f);
        r[2] = y1p; r[3] = (y2p - y1p) * (1.0f / 6.0f);
        r[4] = wz;  r[5] = __int_as_float(off);
        r[6] = 0.0f; r[7] = 0.0f;
    }
    if (tid < 64) wsi[b * 64 + tid] = starts[tid];
}

// ---- kernel 2: block = (z0, slice); lane = (entry, iy) x-row ----
__global__ __launch_bounds__(THREADS, 8) void roialign3d_row_kernel(
    const float* __restrict__ feat,
    const int* __restrict__ wsi,
    const float* __restrict__ wsf,
    float* __restrict__ out)
{
    __shared__ __align__(16) uint2 pk2[64 * SP];   // 33792 B -> 4 blocks/CU

    int bid = blockIdx.x;
    int s   = bid & 511;           // slice fastest -> slice s on XCD s%8 always
    int z0  = bid >> 9;            // 0..62
    int b   = s >> 8;
    int c   = s & 255;
    int tid = threadIdx.x;

    int base = wsi[b * 64 + z0];
    int end  = wsi[b * 64 + z0 + 1];
    if (base == end) return;       // empty bucket: skip staging entirely

    const float* vol = feat + ((size_t)s << 18) + ((size_t)z0 << 12);

    // ---- stage: 2 planes (32 KB) of one slice; 4 float4 loads/thread ----
    int y  = tid >> 3;
    int x8 = (tid & 7) << 3;
    const float* src = vol + y * 64 + x8;
    float4 p0a = *(const float4*)(src);
    float4 p0b = *(const float4*)(src + 4);
    float4 p1a = *(const float4*)(src + 4096);
    float4 p1b = *(const float4*)(src + 4100);

    // lane map: lane = (entry-group g, iy); record prefetch behind plane loads
    int wid  = tid >> 6;
    int lane = tid & 63;
    int g    = lane / 7;               // 0..9 (lane 63 -> g=9, idle)
    int iy   = lane - g * 7;
    float fy = (float)iy;
    const float4* recs = (const float4*)(wsf + REC_F_BASE);
    const int rbase = b * NENT;
    int myEnd = (lane < 63) ? end : base;
    int e = base + wid * 9 + g;
    float4 rA, rB, rAn, rBn;
    if (e < myEnd) {
        rA = recs[(size_t)(rbase + e) * 2];
        rB = recs[(size_t)(rbase + e) * 2 + 1];
        if (e + EPP < myEnd) {
            rAn = recs[(size_t)(rbase + e + EPP) * 2];
            rBn = recs[(size_t)(rbase + e + EPP) * 2 + 1];
        }
    }

    // ---- convert + write: slot64(y,x) = {xpair@z0, xpair@z0+1} ----
    {
        float n0 = __shfl_down(p0a.x, 1);   // next thread's first f32, plane z0
        float n1 = __shfl_down(p1a.x, 1);   // (garbage at row edge: slot x=63
                                            //  upper half, never read)
        uint4* d = (uint4*)&pk2[y * SP + x8];
        uint4 w0, w1, w2, w3;
        w0.x = pkrtz(p0a.x, p0a.y); w0.y = pkrtz(p1a.x, p1a.y);
        w0.z = pkrtz(p0a.y, p0a.z); w0.w = pkrtz(p1a.y, p1a.z);
        w1.x = pkrtz(p0a.z, p0a.w); w1.y = pkrtz(p1a.z, p1a.w);
        w1.z = pkrtz(p0a.w, p0b.x); w1.w = pkrtz(p1a.w, p1b.x);
        w2.x = pkrtz(p0b.x, p0b.y); w2.y = pkrtz(p1b.x, p1b.y);
        w2.z = pkrtz(p0b.y, p0b.z); w2.w = pkrtz(p1b.y, p1b.z);
        w3.x = pkrtz(p0b.z, p0b.w); w3.y = pkrtz(p1b.z, p1b.w);
        w3.z = pkrtz(p0b.w, n0);    w3.w = pkrtz(p1b.w, n1);
        d[0] = w0; d[1] = w1; d[2] = w2; d[3] = w3;
    }
    __syncthreads();

    // ---- entry loop: one lane = one (entry, iy) row of 7 points ----
    float* outc = out + (size_t)c * 343;
    while (e < myEnd) {
        float gx0 = rA.x, sx = rA.y;
        float gy  = fmaf(rA.w, fy, rA.z);
        int   y0  = (int)gy;
        float wy  = __builtin_amdgcn_fractf(gy);
        float wz  = rB.x;
        int  offc = __float_as_int(rB.y);
        int slrow = y0 * SP;
        float* od = outc + offc + iy * 7;

        // rotate record pipeline; prefetch e+2*EPP
        float4 tA = rAn, tB = rBn;
        int e2 = e + 2 * EPP;
        if (e2 < myEnd) {
            rAn = recs[(size_t)(rbase + e2) * 2];
            rBn = recs[(size_t)(rbase + e2) * 2 + 1];
        }

        #pragma unroll
        for (int ix = 0; ix < 7; ++ix) {
            float gx = fmaf(sx, (float)ix, gx0);
            int   x0 = (int)gx;
            float wx = __builtin_amdgcn_fractf(gx);
            uint32_t pw = pkrtz(1.0f - wx, wx);
            int sl = slrow + x0;
            uint2 q0 = pk2[sl];        // row y0   : {z0, z0+1}
            uint2 q1 = pk2[sl + SP];   // row y0+1 : {z0, z0+1}
            float c00 = xlerp(q0.x, pw);
            float c10 = xlerp(q0.y, pw);
            float c01 = xlerp(q1.x, pw);
            float c11 = xlerp(q1.y, pw);
            float d0 = fmaf(c01 - c00, wy, c00);
            float d1 = fmaf(c11 - c10, wy, c10);
            od[ix] = fmaf(d1 - d0, wz, d0);
        }

        e += EPP; rA = tA; rB = tB;
    }
}

// ---- fallback (ws too small): round-1 kernel, known correct ----
__global__ __launch_bounds__(128) void roialign3d_fallback(
    const float* __restrict__ feat, const float* __restrict__ props,
    float* __restrict__ out)
{
    int bid = blockIdx.x;
    int xcd = bid & 7;
    int j   = bid >> 3;
    int s   = xcd + ((j >> 9) << 3);
    int n   = j & 511;
    int b   = s >> 8;
    int c   = s & 255;
    const float* prop = props + ((size_t)(b * N_ + n)) * 6;
    float x1p = prop[0], y1p = prop[1], z1p = prop[2];
    float x2p = prop[3], y2p = prop[4], z2p = prop[5];
    float sx = (x2p - x1p) * (1.0f / 6.0f);
    float sy = (y2p - y1p) * (1.0f / 6.0f);
    float sz = (z2p - z1p) * (1.0f / 6.0f);
    const float* vol = feat + (size_t)s * (64 * 64 * 64);
    float* o = out + ((size_t)(b * N_ + n) * C_ + c) * 343;
    for (int p = threadIdx.x; p < 343; p += 128) {
        int iz = p / 49, r = p - iz * 49, iy = r / 7, ix = r - iy * 7;
        float gx = x1p + sx * ix, gy = y1p + sy * iy, gz = z1p + sz * iz;
        int x0 = (int)gx, y0 = (int)gy, z0 = (int)gz;
        float wx = gx - x0, wy = gy - y0, wz = gz - z0;
        int x1 = min(x0 + 1, 63), y1 = min(y0 + 1, 63), z1 = min(z0 + 1, 63);
        const float* p00 = vol + ((z0 * 64 + y0) << 6);
        const float* p01 = vol + ((z0 * 64 + y1) << 6);
        const float* p10 = vol + ((z1 * 64 + y0) << 6);
        const float* p11 = vol + ((z1 * 64 + y1) << 6);
        float c00 = p00[x0] + (p00[x1] - p00[x0]) * wx;
        float c01 = p01[x0] + (p01[x1] - p01[x0]) * wx;
        float c10 = p10[x0] + (p10[x1] - p10[x0]) * wx;
        float c11 = p11[x0] + (p11[x1] - p11[x0]) * wx;
        float d0 = c00 + (c01 - c00) * wy;
        float d1 = c10 + (c11 - c10) * wy;
        o[p] = d0 + (d1 - d0) * wz;
    }
}

extern "C" void kernel_launch(void* const* d_in, const int* in_sizes, int n_in,
                              void* d_out, int out_size, void* d_ws, size_t ws_size,
                              hipStream_t stream) {
    const float* feat  = (const float*)d_in[0];
    const float* props = (const float*)d_in[1];
    float* out = (float*)d_out;

    if (ws_size < WS_NEEDED) {
        roialign3d_fallback<<<B_ * C_ * N_, 128, 0, stream>>>(feat, props, out);
        return;
    }
    int*   wsi = (int*)d_ws;
    float* wsf = (float*)d_ws;
    bucket_kernel<<<B_, 256, 0, stream>>>(props, wsi, wsf);
    roialign3d_row_kernel<<<63 * 512, THREADS, 0, stream>>>(feat, wsi, wsf, out);
}